// Round 1
// baseline (63.044 us; speedup 1.0000x reference)
//
#include <hip/hip_runtime.h>
#include <math.h>

#define TT 512
#define KP 4
#define PMAXC 64
#define CMAXC 64

// one block per sequence row (bn). 256 threads.
__global__ __launch_bounds__(256) void periodicity_kernel(const float* __restrict__ x,
                                                          float* __restrict__ out) {
    const int bn  = blockIdx.x;     // 0..2047
    const int tid = threadIdx.x;    // 0..255
    const int b = bn >> 6;          // batch
    const int n = bn & 63;          // channel

    __shared__ float  row[TT];          // natural order (for gather)
    __shared__ float4 rowi4[128];       // interleaved: rowi4[r] = {x[r], x[r+128], x[r+256], x[r+384]}
    __shared__ double sval[256];
    __shared__ int    sidx[256];

    // ---- load row: seqs[bn, t] = x[b, t, n], stride 64 floats ----
    const float* xb = x + ((size_t)b * TT) * 64 + n;
    {
        float v0 = xb[(size_t)tid * 64];
        float v1 = xb[(size_t)(tid + 256) * 64];
        row[tid]       = v0;
        row[tid + 256] = v1;
        ((float*)rowi4)[((tid & 127) << 2) | (tid >> 7)]         = v0;
        ((float*)rowi4)[(((tid + 256) & 127) << 2) | ((tid + 256) >> 7)] = v1;
    }
    __syncthreads();

    // ---- DFT bin f = tid+1 (bins 1..256), double precision ----
    const int f = tid + 1;
    const double PI = 3.14159265358979323846;
    double theta = (2.0 * PI / 512.0) * (double)f;
    double wre = cos(theta), wim = sin(theta);
    double zre = 1.0, zim = 0.0;
    double a0r = 0, a0i = 0, a1r = 0, a1i = 0, a2r = 0, a2i = 0, a3r = 0, a3i = 0;
    for (int r = 0; r < 128; ++r) {
        float4 xv = rowi4[r];           // broadcast (uniform address)
        a0r += xv.x * zre; a0i += xv.x * zim;
        a1r += xv.y * zre; a1i += xv.y * zim;
        a2r += xv.z * zre; a2i += xv.z * zim;
        a3r += xv.w * zre; a3i += xv.w * zim;
        double t0 = zre * wre - zim * wim;
        zim = zre * wim + zim * wre;
        zre = t0;
    }
    // combine quadrant accumulators: term factor = i^{(f*q) & 3}
    double Sre = a0r, Sim = a0i;
    {
        int m1 = f & 3, m2 = (2 * f) & 3, m3 = (3 * f) & 3;
        // i^m * (ar + i*ai)
        #define ADDROT(m, ar, ai)                                   \
            switch (m) {                                            \
                case 0: Sre += (ar); Sim += (ai); break;            \
                case 1: Sre -= (ai); Sim += (ar); break;            \
                case 2: Sre -= (ar); Sim -= (ai); break;            \
                case 3: Sre += (ai); Sim -= (ar); break;            \
            }
        ADDROT(m1, a1r, a1i)
        ADDROT(m2, a2r, a2i)
        ADDROT(m3, a3r, a3i)
        #undef ADDROT
    }
    double myval = Sre * Sre + Sim * Sim;   // mag^2 for bin f

    // ---- top-4 (descending, tie -> lower bin index) ----
    int kbin[KP];
    for (int round = 0; round < KP; ++round) {
        sval[tid] = myval;
        sidx[tid] = tid;
        __syncthreads();
        for (int off = 128; off >= 1; off >>= 1) {
            if (tid < off) {
                double v1 = sval[tid], v2 = sval[tid + off];
                int    i1 = sidx[tid], i2 = sidx[tid + off];
                if (v2 > v1 || (v2 == v1 && i2 < i1)) { sval[tid] = v2; sidx[tid] = i2; }
            }
            __syncthreads();
        }
        int win = sidx[0];
        kbin[round] = win + 1;      // bin index (freq)
        __syncthreads();            // protect sval/sidx[0] before next round's writes
        if (tid == win) myval = -1.0;
    }

    // ---- periods / cycles / start (uniform across threads) ----
    int per[KP], cyc[KP], st[KP];
    #pragma unroll
    for (int k = 0; k < KP; ++k) {
        int p = TT / kbin[k];
        p = p < 8 ? 8 : (p > 64 ? 64 : p);
        per[k] = p;
        cyc[k] = TT / p;
        st[k]  = TT - cyc[k] * p;
    }

    const size_t VOFF = (size_t)2048 * KP * CMAXC * PMAXC;  // 33,554,432
    if (tid == 0) {
        #pragma unroll
        for (int k = 0; k < KP; ++k) {
            out[VOFF + (size_t)bn * KP + k]        = (float)per[k];
            out[VOFF + 8192 + (size_t)bn * KP + k] = (float)cyc[k];
        }
    }

    // ---- gather + write values[bn, k, c, p], zero-padded ----
    // e = it*256 + tid ; k = it>>4 (compile-time under unroll); wave covers p=0..63
    float* outv = out + (size_t)bn * (KP * CMAXC * PMAXC);
    #pragma unroll
    for (int it = 0; it < 64; ++it) {
        const int k = it >> 4;
        int c = ((it & 15) << 2) + (tid >> 6);
        int p = tid & 63;
        float v = 0.0f;
        if (c < cyc[k] && p < per[k])
            v = row[st[k] + c * per[k] + p];
        outv[it * 256 + tid] = v;
    }
}

extern "C" void kernel_launch(void* const* d_in, const int* in_sizes, int n_in,
                              void* d_out, int out_size, void* d_ws, size_t ws_size,
                              hipStream_t stream) {
    const float* x = (const float*)d_in[0];
    float* out = (float*)d_out;
    hipLaunchKernelGGL(periodicity_kernel, dim3(2048), dim3(256), 0, stream, x, out);
}

// Round 2
// 55.481 us; speedup vs baseline: 1.1363x; 1.1363x over previous
//
#include <hip/hip_runtime.h>
#include <math.h>

#define TT 512
#define KP 4

// one block per sequence row (bn = b*64 + n). 256 threads = 4 waves.
__global__ __launch_bounds__(256) void periodicity_kernel(const float* __restrict__ x,
                                                          float* __restrict__ out) {
    const int bn   = blockIdx.x;     // 0..2047
    const int tid  = threadIdx.x;    // 0..255
    const int lane = tid & 63;
    const int wid  = tid >> 6;
    const int b = bn >> 6;
    const int n = bn & 63;

    __shared__ float  row[TT];        // natural order
    __shared__ float  rowi[TT];       // rowi[(t&63)*8 + (t>>6)]  (8-way split layout)
    __shared__ int    candBin[32];    // per-wave top-8 bins (f values)
    __shared__ float  candValF[32];
    __shared__ int    fin8[8];        // global top-8 candidate bins
    __shared__ double candV8[8];      // f64-refined mag^2 of those bins

    // ---- load row: seqs[bn, t] = x[b, t, n] (stride-64 column) ----
    const float* xb = x + (size_t)b * (TT * 64) + n;
    {
        float v0 = xb[(size_t)tid * 64];
        float v1 = xb[(size_t)(tid + 256) * 64];
        int t0 = tid, t1 = tid + 256;
        row[t0] = v0;  row[t1] = v1;
        rowi[(t0 & 63) * 8 + (t0 >> 6)] = v0;
        rowi[(t1 & 63) * 8 + (t1 >> 6)] = v1;
    }
    __syncthreads();

    // ---- fp32 screening DFT, bin f = tid+1 (1..256) ----
    // S(f) = sum_t x[t] e^{i th t},  th = 2*pi*f/512.  Split t = r + 64q.
    const int f = tid + 1;
    float th = (float)(2.0 * M_PI / 512.0) * (float)f;
    float wre, wim;
    sincosf(th, &wim, &wre);
    float zre = 1.0f, zim = 0.0f;
    float2 acc[8];
    #pragma unroll
    for (int q = 0; q < 8; ++q) acc[q] = make_float2(0.f, 0.f);

    const float4* r4 = (const float4*)rowi;
    #pragma unroll 8
    for (int r = 0; r < 64; ++r) {
        float4 s0 = r4[r * 2];       // q = 0..3  (broadcast)
        float4 s1 = r4[r * 2 + 1];   // q = 4..7
        acc[0].x = fmaf(s0.x, zre, acc[0].x); acc[0].y = fmaf(s0.x, zim, acc[0].y);
        acc[1].x = fmaf(s0.y, zre, acc[1].x); acc[1].y = fmaf(s0.y, zim, acc[1].y);
        acc[2].x = fmaf(s0.z, zre, acc[2].x); acc[2].y = fmaf(s0.z, zim, acc[2].y);
        acc[3].x = fmaf(s0.w, zre, acc[3].x); acc[3].y = fmaf(s0.w, zim, acc[3].y);
        acc[4].x = fmaf(s1.x, zre, acc[4].x); acc[4].y = fmaf(s1.x, zim, acc[4].y);
        acc[5].x = fmaf(s1.y, zre, acc[5].x); acc[5].y = fmaf(s1.y, zim, acc[5].y);
        acc[6].x = fmaf(s1.z, zre, acc[6].x); acc[6].y = fmaf(s1.z, zim, acc[6].y);
        acc[7].x = fmaf(s1.w, zre, acc[7].x); acc[7].y = fmaf(s1.w, zim, acc[7].y);
        float t0 = zre * wre - zim * wim;
        zim = fmaf(zre, wim, zim * wre);
        zre = t0;
    }
    // combine: S = sum_q A_q * e^{i*pi*f*q/4}  (8th roots of unity)
    float c8, s8;
    sincosf((float)(f & 7) * 0.78539816339744831f, &s8, &c8);
    float cre = 1.0f, cim = 0.0f;
    float Sre = 0.0f, Sim = 0.0f;
    #pragma unroll
    for (int q = 0; q < 8; ++q) {
        Sre += acc[q].x * cre - acc[q].y * cim;
        Sim += acc[q].x * cim + acc[q].y * cre;
        float t0 = cre * c8 - cim * s8;
        cim = fmaf(cre, s8, cim * c8);
        cre = t0;
    }
    float mag = Sre * Sre + Sim * Sim;

    // ---- per-wave top-8 (value desc, bin asc) via shfl butterflies ----
    {
        float v = mag;
        #pragma unroll
        for (int r = 0; r < 8; ++r) {
            float cv = v; int ci = f;
            #pragma unroll
            for (int off = 32; off >= 1; off >>= 1) {
                float ov = __shfl_xor(cv, off);
                int   oi = __shfl_xor(ci, off);
                if (ov > cv || (ov == cv && oi < ci)) { cv = ov; ci = oi; }
            }
            if (lane == 0) { candBin[wid * 8 + r] = ci; candValF[wid * 8 + r] = cv; }
            if (f == ci) v = -1.0f;   // remove winner
        }
    }
    __syncthreads();

    // ---- global top-8 among the 32 candidates (wave 0 only) ----
    if (wid == 0) {
        float cv = (lane < 32) ? candValF[lane] : -2.0f;
        int   ci = (lane < 32) ? candBin[lane]  : 0x7fffffff;
        #pragma unroll
        for (int r = 0; r < 8; ++r) {
            float bv = cv; int bi = ci;
            #pragma unroll
            for (int off = 32; off >= 1; off >>= 1) {
                float ov = __shfl_xor(bv, off);
                int   oi = __shfl_xor(bi, off);
                if (ov > bv || (ov == bv && oi < bi)) { bv = ov; bi = oi; }
            }
            if (lane == 0) fin8[r] = bi;
            if (ci == bi) cv = -1.5f;   // removed; still > inactive sentinel, never re-picked
        }
    }
    __syncthreads();

    // ---- f64 refine of the 8 candidates: exact mag^2 ranking ----
    {
        const int cid = tid >> 5;        // candidate 0..7
        const int sub = tid & 31;        // 32 threads per candidate
        const int fc  = fin8[cid];
        const int t0  = sub * 16;        // 16 consecutive samples per thread
        const double W = 6.2831853071795864769 / 512.0;
        double zr, zi, wr, wi;
        double th0 = W * (double)((fc * t0) & 511);
        sincos(th0, &zi, &zr);
        double thw = W * (double)fc;
        sincos(thw, &wi, &wr);
        double ar = 0.0, ai = 0.0;
        #pragma unroll
        for (int i = 0; i < 16; ++i) {
            double xv = (double)row[t0 + i];
            ar = fma(xv, zr, ar);
            ai = fma(xv, zi, ai);
            double tq = zr * wr - zi * wi;
            zi = fma(zr, wi, zi * wr);
            zr = tq;
        }
        #pragma unroll
        for (int off = 16; off >= 1; off >>= 1) {
            ar += __shfl_xor(ar, off);
            ai += __shfl_xor(ai, off);
        }
        if (sub == 0) candV8[cid] = ar * ar + ai * ai;
    }
    __syncthreads();

    // ---- final top-4 (uniform serial over 8 candidates, tie -> lower bin) ----
    int per[KP], cyc[KP], st[KP];
    {
        unsigned chosen = 0;
        #pragma unroll
        for (int k = 0; k < KP; ++k) {
            double bv = -1.0; int bbin = 0x7fffffff; int bj = 0;
            #pragma unroll
            for (int j = 0; j < 8; ++j) {
                if (chosen & (1u << j)) continue;
                double vj = candV8[j];
                int    bjn = fin8[j];
                if (vj > bv || (vj == bv && bjn < bbin)) { bv = vj; bbin = bjn; bj = j; }
            }
            chosen |= (1u << bj);
            int p = TT / bbin;
            p = p < 8 ? 8 : (p > 64 ? 64 : p);
            per[k] = p;
            cyc[k] = TT / p;
            st[k]  = TT - cyc[k] * p;
        }
    }

    const size_t VOFF = (size_t)2048 * KP * 64 * 64;   // 33,554,432
    if (tid == 0) {
        #pragma unroll
        for (int k = 0; k < KP; ++k) {
            out[VOFF + (size_t)bn * KP + k]        = (float)per[k];
            out[VOFF + 8192 + (size_t)bn * KP + k] = (float)cyc[k];
        }
    }

    // ---- gather + vectorized write: values[bn, k, c, p] ----
    // per iter: one k, 16 c-rows; thread -> c = (it&3)*16 + (tid>>4), p0 = (tid&15)*4
    float* outv = out + (size_t)bn * (KP * 64 * 64);
    const int c_local = tid >> 4;
    const int p0 = (tid & 15) << 2;
    #pragma unroll
    for (int it = 0; it < 16; ++it) {
        const int k = it >> 2;
        const int c = ((it & 3) << 4) + c_local;
        float4 v = make_float4(0.f, 0.f, 0.f, 0.f);
        const int P = per[k], C = cyc[k], S0 = st[k];
        if (c < C) {
            const int base = S0 + c * P;
            if (p0 + 3 < P) {
                v.x = row[base + p0];
                v.y = row[base + p0 + 1];
                v.z = row[base + p0 + 2];
                v.w = row[base + p0 + 3];
            } else {
                v.x = (p0 + 0 < P) ? row[base + p0]     : 0.f;
                v.y = (p0 + 1 < P) ? row[base + p0 + 1] : 0.f;
                v.z = (p0 + 2 < P) ? row[base + p0 + 2] : 0.f;
                v.w = (p0 + 3 < P) ? row[base + p0 + 3] : 0.f;
            }
        }
        *(float4*)(outv + (size_t)it * 1024 + (size_t)tid * 4) = v;
    }
}

extern "C" void kernel_launch(void* const* d_in, const int* in_sizes, int n_in,
                              void* d_out, int out_size, void* d_ws, size_t ws_size,
                              hipStream_t stream) {
    const float* x = (const float*)d_in[0];
    float* out = (float*)d_out;
    hipLaunchKernelGGL(periodicity_kernel, dim3(2048), dim3(256), 0, stream, x, out);
}

// Round 3
// 41.713 us; speedup vs baseline: 1.5114x; 1.3301x over previous
//
#include <hip/hip_runtime.h>
#include <math.h>

#define TT 512
#define KP 4

// one block per sequence row (bn = b*64 + n). 256 threads = 4 waves.
__global__ __launch_bounds__(256) void periodicity_kernel(const float* __restrict__ x,
                                                          float* __restrict__ out) {
    const int bn   = blockIdx.x;     // 0..2047
    const int tid  = threadIdx.x;    // 0..255
    const int lane = tid & 63;
    const int wid  = tid >> 6;
    const int b = bn >> 6;
    const int n = bn & 63;

    __shared__ float  row[TT];        // natural order (gather + f64 refine)
    __shared__ float2 buf[TT];        // FFT working buffer
    __shared__ float2 tw[256];        // tw[k] = e^{-2*pi*i*k/512}
    __shared__ float  magbin[256];    // mag^2 for bins f = 1..256
    __shared__ int    candBin[32];
    __shared__ float  candValF[32];
    __shared__ int    fin8[8];
    __shared__ double candV8[8];

    // ---- twiddle table (one sincosf per thread) ----
    {
        float s, c;
        sincosf((float)(2.0 * M_PI / 512.0) * (float)tid, &s, &c);
        tw[tid] = make_float2(c, -s);
    }

    // ---- load row: seqs[bn, t] = x[b, t, n] (stride-64 column) ----
    const float* xb = x + (size_t)b * (TT * 64) + n;
    {
        float v0 = xb[(size_t)tid * 64];
        float v1 = xb[(size_t)(tid + 256) * 64];
        row[tid]       = v0;  row[tid + 256] = v1;
        buf[tid]       = make_float2(v0, 0.f);
        buf[tid + 256] = make_float2(v1, 0.f);
    }
    __syncthreads();

    // ---- 9-stage radix-2 DIF FFT (in-place, pairs disjoint per stage) ----
    #pragma unroll
    for (int s = 0; s < 9; ++s) {
        const int half = 256 >> s;
        const int pos  = tid & (half - 1);
        const int i0   = ((tid >> (8 - s)) << (9 - s)) + pos;
        const int i1   = i0 + half;
        float2 a  = buf[i0];
        float2 bb = buf[i1];
        float2 t  = tw[pos << s];
        float dr = a.x - bb.x, di = a.y - bb.y;
        buf[i0] = make_float2(a.x + bb.x, a.y + bb.y);
        buf[i1] = make_float2(dr * t.x - di * t.y, dr * t.y + di * t.x);
        __syncthreads();
    }

    // ---- scatter mag^2 to bin order (output is bit-reversed) ----
    #pragma unroll
    for (int h = 0; h < 2; ++h) {
        int r = tid + h * 256;
        int fb = (int)(__brev((unsigned)r) >> 23);   // bitrev9
        if (fb >= 1 && fb <= 256) {
            float2 v = buf[r];
            magbin[fb - 1] = v.x * v.x + v.y * v.y;
        }
    }
    __syncthreads();

    const int f = tid + 1;            // this thread's bin
    float mag = magbin[tid];

    // ---- per-wave top-8 (value desc, bin asc) via shfl butterflies ----
    {
        float v = mag;
        #pragma unroll
        for (int r = 0; r < 8; ++r) {
            float cv = v; int ci = f;
            #pragma unroll
            for (int off = 32; off >= 1; off >>= 1) {
                float ov = __shfl_xor(cv, off);
                int   oi = __shfl_xor(ci, off);
                if (ov > cv || (ov == cv && oi < ci)) { cv = ov; ci = oi; }
            }
            if (lane == 0) { candBin[wid * 8 + r] = ci; candValF[wid * 8 + r] = cv; }
            if (f == ci) v = -1.0f;   // remove winner
        }
    }
    __syncthreads();

    // ---- global top-8 among the 32 candidates (wave 0 only) ----
    if (wid == 0) {
        float cv = (lane < 32) ? candValF[lane] : -2.0f;
        int   ci = (lane < 32) ? candBin[lane]  : 0x7fffffff;
        #pragma unroll
        for (int r = 0; r < 8; ++r) {
            float bv = cv; int bi = ci;
            #pragma unroll
            for (int off = 32; off >= 1; off >>= 1) {
                float ov = __shfl_xor(bv, off);
                int   oi = __shfl_xor(bi, off);
                if (ov > bv || (ov == bv && oi < bi)) { bv = ov; bi = oi; }
            }
            if (lane == 0) fin8[r] = bi;
            if (ci == bi) cv = -1.5f;   // removed; still above inactive sentinel
        }
    }
    __syncthreads();

    // ---- f64 refine of the 8 candidates: exact mag^2 ranking ----
    {
        const int cid = tid >> 5;        // candidate 0..7
        const int sub = tid & 31;        // 32 threads per candidate
        const int fc  = fin8[cid];
        const int t0  = sub * 16;        // 16 consecutive samples per thread
        const double W = 6.2831853071795864769 / 512.0;
        double zr, zi, wr, wi;
        double th0 = W * (double)((fc * t0) & 511);
        sincos(th0, &zi, &zr);
        double thw = W * (double)fc;
        sincos(thw, &wi, &wr);
        double ar = 0.0, ai = 0.0;
        #pragma unroll
        for (int i = 0; i < 16; ++i) {
            double xv = (double)row[t0 + i];
            ar = fma(xv, zr, ar);
            ai = fma(xv, zi, ai);
            double tq = zr * wr - zi * wi;
            zi = fma(zr, wi, zi * wr);
            zr = tq;
        }
        #pragma unroll
        for (int off = 16; off >= 1; off >>= 1) {
            ar += __shfl_xor(ar, off);
            ai += __shfl_xor(ai, off);
        }
        if (sub == 0) candV8[cid] = ar * ar + ai * ai;
    }
    __syncthreads();

    // ---- final top-4 (uniform serial over 8 candidates, tie -> lower bin) ----
    int per[KP], cyc[KP], st[KP];
    {
        unsigned chosen = 0;
        #pragma unroll
        for (int k = 0; k < KP; ++k) {
            double bv = -1.0; int bbin = 0x7fffffff; int bj = 0;
            #pragma unroll
            for (int j = 0; j < 8; ++j) {
                if (chosen & (1u << j)) continue;
                double vj = candV8[j];
                int    bjn = fin8[j];
                if (vj > bv || (vj == bv && bjn < bbin)) { bv = vj; bbin = bjn; bj = j; }
            }
            chosen |= (1u << bj);
            int p = TT / bbin;
            p = p < 8 ? 8 : (p > 64 ? 64 : p);
            per[k] = p;
            cyc[k] = TT / p;
            st[k]  = TT - cyc[k] * p;
        }
    }

    const size_t VOFF = (size_t)2048 * KP * 64 * 64;   // 33,554,432
    if (tid == 0) {
        #pragma unroll
        for (int k = 0; k < KP; ++k) {
            out[VOFF + (size_t)bn * KP + k]        = (float)per[k];
            out[VOFF + 8192 + (size_t)bn * KP + k] = (float)cyc[k];
        }
    }

    // ---- gather + vectorized write: values[bn, k, c, p] ----
    float* outv = out + (size_t)bn * (KP * 64 * 64);
    const int c_local = tid >> 4;
    const int p0 = (tid & 15) << 2;
    #pragma unroll
    for (int it = 0; it < 16; ++it) {
        const int k = it >> 2;
        const int c = ((it & 3) << 4) + c_local;
        float4 v = make_float4(0.f, 0.f, 0.f, 0.f);
        const int P = per[k], C = cyc[k], S0 = st[k];
        if (c < C) {
            const int base = S0 + c * P;
            if (p0 + 3 < P) {
                v.x = row[base + p0];
                v.y = row[base + p0 + 1];
                v.z = row[base + p0 + 2];
                v.w = row[base + p0 + 3];
            } else {
                v.x = (p0 + 0 < P) ? row[base + p0]     : 0.f;
                v.y = (p0 + 1 < P) ? row[base + p0 + 1] : 0.f;
                v.z = (p0 + 2 < P) ? row[base + p0 + 2] : 0.f;
                v.w = (p0 + 3 < P) ? row[base + p0 + 3] : 0.f;
            }
        }
        *(float4*)(outv + (size_t)it * 1024 + (size_t)tid * 4) = v;
    }
}

extern "C" void kernel_launch(void* const* d_in, const int* in_sizes, int n_in,
                              void* d_out, int out_size, void* d_ws, size_t ws_size,
                              hipStream_t stream) {
    const float* x = (const float*)d_in[0];
    float* out = (float*)d_out;
    hipLaunchKernelGGL(periodicity_kernel, dim3(2048), dim3(256), 0, stream, x, out);
}

// Round 4
// 33.728 us; speedup vs baseline: 1.8692x; 1.2367x over previous
//
#include <hip/hip_runtime.h>
#include <math.h>

#define TT 512
#define KP 4

typedef unsigned long long u64;

// one block per sequence row (bn = b*64 + n). 256 threads = 4 waves.
__global__ __launch_bounds__(256) void periodicity_kernel(const float* __restrict__ x,
                                                          float* __restrict__ out) {
    const int bn   = blockIdx.x;     // 0..2047
    const int tid  = threadIdx.x;    // 0..255
    const int lane = tid & 63;
    const int wid  = tid >> 6;
    const int b = bn >> 6;
    const int n = bn & 63;

    __shared__ float  row[TT];        // natural order (gather + f64 refine)
    __shared__ float2 buf[TT];        // FFT working buffer
    __shared__ float2 tw[TT];         // tw[m] = e^{-2*pi*i*m/512}
    __shared__ u64    keys[256];      // packed (mag_bits<<32)|(255-(f-1)) per bin
    __shared__ int    fin8[8];        // global top-8 candidate bins
    __shared__ double candV8[8];      // f64-refined mag^2 of those bins

    // ---- twiddles: tw[m] and tw[m+256] = -tw[m] (one sincosf/thread) ----
    float sv, cv_;
    sincosf((float)(2.0 * M_PI / 512.0) * (float)tid, &sv, &cv_);
    tw[tid]       = make_float2(cv_, -sv);
    tw[tid + 256] = make_float2(-cv_, sv);

    // ---- load row (stride-64 column) + folded radix-2 first DIF stage ----
    // pair (t, t+256) is exactly the radix-2 butterfly; twiddle = tw[tid]
    const float* xb = x + (size_t)b * (TT * 64) + n;
    {
        float v0 = xb[(size_t)tid * 64];
        float v1 = xb[(size_t)(tid + 256) * 64];
        row[tid] = v0;  row[tid + 256] = v1;
        float sum = v0 + v1, dif = v0 - v1;
        buf[tid]       = make_float2(sum, 0.f);
        buf[tid + 256] = make_float2(dif * cv_, -dif * sv);
    }
    __syncthreads();

    // ---- 4 radix-4 DIF stages on each 256-half (128 active threads) ----
    #pragma unroll
    for (int stg = 0; stg < 4; ++stg) {
        if (tid < 128) {
            const int Q  = 64 >> (2 * stg);          // 64,16,4,1
            const int B4 = Q << 2;
            const int h  = tid >> 6;
            const int j  = tid & 63;
            const int g  = j >> (6 - 2 * stg);       // j / Q
            const int i  = j & (Q - 1);
            const int base = (h << 8) + g * B4 + i;
            float2 x0 = buf[base], x1 = buf[base + Q];
            float2 x2 = buf[base + 2 * Q], x3 = buf[base + 3 * Q];
            float2 A  = make_float2(x0.x + x2.x, x0.y + x2.y);
            float2 Bm = make_float2(x0.x - x2.x, x0.y - x2.y);
            float2 Cc = make_float2(x1.x + x3.x, x1.y + x3.y);
            float2 D  = make_float2(x1.x - x3.x, x1.y - x3.y);
            float2 y0 = make_float2(A.x + Cc.x, A.y + Cc.y);
            float2 y2 = make_float2(A.x - Cc.x, A.y - Cc.y);
            float2 y1 = make_float2(Bm.x + D.y, Bm.y - D.x);   // Bm - i*D
            float2 y3 = make_float2(Bm.x - D.y, Bm.y + D.x);   // Bm + i*D
            const int m = i << (1 + 2 * stg);         // i * (512/B4); 3m < 512
            float2 t1 = tw[m], t2 = tw[2 * m], t3 = tw[3 * m];
            buf[base]         = y0;
            buf[base + Q]     = make_float2(y1.x * t1.x - y1.y * t1.y, y1.x * t1.y + y1.y * t1.x);
            buf[base + 2 * Q] = make_float2(y2.x * t2.x - y2.y * t2.y, y2.x * t2.y + y2.y * t2.x);
            buf[base + 3 * Q] = make_float2(y3.x * t3.x - y3.y * t3.y, y3.x * t3.y + y3.y * t3.x);
        }
        __syncthreads();
    }

    // ---- scatter |X|^2 into packed keys (output is base-4 digit-reversed) ----
    // pos = h*256 + p  holds bin f = 2*digitrev4(p) + h
    #pragma unroll
    for (int hh = 0; hh < 2; ++hh) {
        int pos = tid + hh * 256;
        int p = pos & 255;
        int kprime = ((p & 3) << 6) | (((p >> 2) & 3) << 4) | (((p >> 4) & 3) << 2) | ((p >> 6) & 3);
        int f = 2 * kprime + hh;
        if (f >= 1 && f <= 256) {
            float2 v = buf[pos];
            float mag = v.x * v.x + v.y * v.y;
            keys[f - 1] = ((u64)__float_as_uint(mag) << 32) | (u64)(255 - (f - 1));
        }
    }
    __syncthreads();

    // ---- top-8 of 256 keys: wave 0 only (value desc, bin asc) ----
    if (wid == 0) {
        u64 k0 = keys[lane * 4 + 0];
        u64 k1 = keys[lane * 4 + 1];
        u64 k2 = keys[lane * 4 + 2];
        u64 k3 = keys[lane * 4 + 3];
        #define CSWAP(a, b) { if (a < b) { u64 _t = a; a = b; b = _t; } }
        CSWAP(k0, k1) CSWAP(k2, k3) CSWAP(k0, k2) CSWAP(k1, k3) CSWAP(k1, k2)
        #undef CSWAP
        #pragma unroll
        for (int r = 0; r < 8; ++r) {
            u64 w = k0;
            #pragma unroll
            for (int off = 32; off >= 1; off >>= 1) {
                u64 o = __shfl_xor(w, off);
                if (o > w) w = o;
            }
            if (k0 == w) { k0 = k1; k1 = k2; k2 = k3; k3 = 0; }   // unique owner pops
            if (lane == 0) fin8[r] = 256 - (int)(w & 0xff);
        }
    }
    __syncthreads();

    // ---- f64 refine of the 8 candidates: exact mag^2 ranking ----
    {
        const int cid = tid >> 5;        // candidate 0..7
        const int sub = tid & 31;        // 32 threads per candidate
        const int fc  = fin8[cid];
        const int t0  = sub * 16;        // 16 consecutive samples per thread
        const double W = 6.2831853071795864769 / 512.0;
        double zr, zi, wr, wi;
        sincos(W * (double)((fc * t0) & 511), &zi, &zr);
        sincos(W * (double)fc, &wi, &wr);
        double ar = 0.0, ai = 0.0;
        const float4* r4 = (const float4*)row;
        #pragma unroll
        for (int v4i = 0; v4i < 4; ++v4i) {
            float4 xv = r4[sub * 4 + v4i];
            #define STEP(comp)                                   \
                { double xd = (double)xv.comp;                   \
                  ar = fma(xd, zr, ar); ai = fma(xd, zi, ai);    \
                  double tq = zr * wr - zi * wi;                 \
                  zi = fma(zr, wi, zi * wr); zr = tq; }
            STEP(x) STEP(y) STEP(z) STEP(w)
            #undef STEP
        }
        #pragma unroll
        for (int off = 16; off >= 1; off >>= 1) {
            ar += __shfl_xor(ar, off);
            ai += __shfl_xor(ai, off);
        }
        if (sub == 0) candV8[cid] = ar * ar + ai * ai;
    }
    __syncthreads();

    // ---- final top-4 (uniform serial over 8 candidates, tie -> lower bin) ----
    int per[KP], cyc[KP], st[KP];
    {
        unsigned chosen = 0;
        #pragma unroll
        for (int k = 0; k < KP; ++k) {
            double bv = -1.0; int bbin = 0x7fffffff; int bj = 0;
            #pragma unroll
            for (int j = 0; j < 8; ++j) {
                if (chosen & (1u << j)) continue;
                double vj = candV8[j];
                int    bjn = fin8[j];
                if (vj > bv || (vj == bv && bjn < bbin)) { bv = vj; bbin = bjn; bj = j; }
            }
            chosen |= (1u << bj);
            int p = TT / bbin;
            p = p < 8 ? 8 : (p > 64 ? 64 : p);
            per[k] = p;
            cyc[k] = TT / p;
            st[k]  = TT - cyc[k] * p;
        }
    }

    const size_t VOFF = (size_t)2048 * KP * 64 * 64;   // 33,554,432
    if (tid == 0) {
        #pragma unroll
        for (int k = 0; k < KP; ++k) {
            out[VOFF + (size_t)bn * KP + k]        = (float)per[k];
            out[VOFF + 8192 + (size_t)bn * KP + k] = (float)cyc[k];
        }
    }

    // ---- gather + vectorized write: values[bn, k, c, p] ----
    float* outv = out + (size_t)bn * (KP * 64 * 64);
    const int c_local = tid >> 4;
    const int p0 = (tid & 15) << 2;
    #pragma unroll
    for (int it = 0; it < 16; ++it) {
        const int k = it >> 2;
        const int c = ((it & 3) << 4) + c_local;
        float4 v = make_float4(0.f, 0.f, 0.f, 0.f);
        const int P = per[k], C = cyc[k], S0 = st[k];
        if (c < C) {
            const int base = S0 + c * P;
            if (p0 + 3 < P) {
                v.x = row[base + p0];
                v.y = row[base + p0 + 1];
                v.z = row[base + p0 + 2];
                v.w = row[base + p0 + 3];
            } else {
                v.x = (p0 + 0 < P) ? row[base + p0]     : 0.f;
                v.y = (p0 + 1 < P) ? row[base + p0 + 1] : 0.f;
                v.z = (p0 + 2 < P) ? row[base + p0 + 2] : 0.f;
                v.w = (p0 + 3 < P) ? row[base + p0 + 3] : 0.f;
            }
        }
        *(float4*)(outv + (size_t)it * 1024 + (size_t)tid * 4) = v;
    }
}

extern "C" void kernel_launch(void* const* d_in, const int* in_sizes, int n_in,
                              void* d_out, int out_size, void* d_ws, size_t ws_size,
                              hipStream_t stream) {
    const float* x = (const float*)d_in[0];
    float* out = (float*)d_out;
    hipLaunchKernelGGL(periodicity_kernel, dim3(2048), dim3(256), 0, stream, x, out);
}